// Round 2
// baseline (438.275 us; speedup 1.0000x reference)
//
#include <hip/hip_runtime.h>
#include <math.h>

// Problem constants (from setup_inputs)
#define BB 4
#define CC 64
#define HH 128
#define WW 128
#define OO 64
#define HWW (HH * WW)
#define KK 9      // 3x3 taps
#define NOM 27    // DG*3*K offset/mask channels

// ws layout (floats) — only transposed weights now (~210 KB total):
//   wt2  : [0,     36864)   [c][k][o]  64*9*64
//   wom2 : [36864, 52416)   [c][t][j]  64*9*27
#define WT2_OFF  0
#define WOM2_OFF 36864

// ---------------------------------------------------------------------------
// Kernel 0: transpose weights so the inner reductions read contiguous,
// wave-uniform rows (scalar-cache friendly).
__global__ void prep_kernel(const float* __restrict__ weight,     // (O,C,3,3)
                            const float* __restrict__ om_weight,  // (27,C,3,3)
                            float* __restrict__ wt2,              // (C,9,O)
                            float* __restrict__ wom2)             // (C,9,27)
{
    int d = blockIdx.x * 256 + threadIdx.x;
    if (d < OO * CC * KK) {
        // dst index d = (c*9 + k)*64 + o
        int o  = d & 63;
        int ck = d >> 6;
        int k  = ck % 9;
        int c  = ck / 9;
        wt2[d] = weight[(o * CC + c) * 9 + k];
    }
    int d2 = d - OO * CC * KK;
    if (d2 >= 0 && d2 < NOM * CC * KK) {
        // dst index d2 = (c*9 + t)*27 + j
        int j  = d2 % 27;
        int ct = d2 / 27;
        int t  = ct % 9;
        int c  = ct / 9;
        wom2[d2] = om_weight[(j * CC + c) * 9 + t];
    }
}

// ---------------------------------------------------------------------------
// Fused kernel: per output pixel —
//   phase 1: 3x3x64 offset/mask conv -> 27 in-register values (+bias, sigmoid)
//   phase 2: per tap k: bilinear sample weights from om, then over c:
//            sample x, FMA into 64 output-channel accumulators.
// Weight rows wt2[(c*9+k)*64 + o] are wave-uniform -> scalar loads; the
// inner o-loop is 64 x v_fmac(vgpr, sgpr, vgpr).
__global__ void __launch_bounds__(256, 2)
fused_kernel(const float* __restrict__ x,     // (B,C,H,W)
             const float* __restrict__ wt2,   // (C,9,O)
             const float* __restrict__ bias,  // (O)
             const float* __restrict__ wom2,  // (C,9,27)
             const float* __restrict__ om_bias,
             float* __restrict__ out)         // (B,O,H,W)
{
    int tid = blockIdx.x * 256 + threadIdx.x;
    if (tid >= BB * HWW) return;
    int b  = tid / HWW;
    int p  = tid - b * HWW;
    int ho = p / WW;
    int wo = p - ho * WW;

    const float* xb = x + (size_t)b * CC * HWW;

    // ---------------- phase 1: offset/mask conv ----------------
    float om[NOM];
#pragma unroll
    for (int j = 0; j < NOM; j++) om[j] = 0.f;

#pragma unroll 1
    for (int c = 0; c < CC; c++) {
        const float* xc = xb + c * HWW;
        float v[9];
#pragma unroll
        for (int t = 0; t < 9; t++) {
            int y  = ho + t / 3 - 1;
            int xw = wo + t % 3 - 1;
            bool ok = (y >= 0) & (y < HH) & (xw >= 0) & (xw < WW);
            v[t] = ok ? xc[y * WW + xw] : 0.f;
        }
#pragma unroll
        for (int t = 0; t < 9; t++) {
            const float* wr = wom2 + (c * 9 + t) * NOM;
#pragma unroll
            for (int j = 0; j < NOM; j++) om[j] += v[t] * wr[j];
        }
    }
#pragma unroll
    for (int j = 0; j < NOM; j++) om[j] += om_bias[j];

    // ---------------- phase 2: deformable conv ----------------
    float acc[OO];
#pragma unroll
    for (int o = 0; o < OO; o++) acc[o] = 0.f;

#pragma unroll 1
    for (int k = 0; k < KK; k++) {
        int ky = k / 3, kx = k % 3;
        float oy = om[k];
        float ox = om[9 + k];
        float m  = 1.f / (1.f + expf(-om[18 + k]));

        float py = oy + (float)(ho - 1 + ky);
        float px = ox + (float)(wo - 1 + kx);
        float fy0 = floorf(py);
        float fx0 = floorf(px);
        float ly = py - fy0;
        float lx = px - fx0;
        int y0 = (int)fy0;
        int x0 = (int)fx0;
        int y1 = y0 + 1;
        int x1 = x0 + 1;

        bool vy0 = (y0 >= 0) & (y0 < HH);
        bool vy1 = (y1 >= 0) & (y1 < HH);
        bool vx0 = (x0 >= 0) & (x0 < WW);
        bool vx1 = (x1 >= 0) & (x1 < WW);

        float w00 = (vy0 & vx0) ? (1.f - ly) * (1.f - lx) * m : 0.f;
        float w01 = (vy0 & vx1) ? (1.f - ly) * lx * m : 0.f;
        float w10 = (vy1 & vx0) ? ly * (1.f - lx) * m : 0.f;
        float w11 = (vy1 & vx1) ? ly * lx * m : 0.f;

        int cy0 = min(max(y0, 0), HH - 1);
        int cy1 = min(max(y1, 0), HH - 1);
        int cx0 = min(max(x0, 0), WW - 1);
        int cx1 = min(max(x1, 0), WW - 1);
        int i00 = cy0 * WW + cx0;
        int i01 = cy0 * WW + cx1;
        int i10 = cy1 * WW + cx0;
        int i11 = cy1 * WW + cx1;

#pragma unroll 2
        for (int c = 0; c < CC; c++) {
            const float* xc = xb + c * HWW;
            float v = w00 * xc[i00] + w01 * xc[i01]
                    + w10 * xc[i10] + w11 * xc[i11];
            const float* wr = wt2 + (c * 9 + k) * OO;
#pragma unroll
            for (int o = 0; o < OO; o++) acc[o] += v * wr[o];
        }
    }

#pragma unroll
    for (int o = 0; o < OO; o++) {
        out[((size_t)(b * OO + o)) * HWW + p] = acc[o] + bias[o];
    }
}

// ---------------------------------------------------------------------------
extern "C" void kernel_launch(void* const* d_in, const int* in_sizes, int n_in,
                              void* d_out, int out_size, void* d_ws, size_t ws_size,
                              hipStream_t stream)
{
    (void)in_sizes; (void)n_in; (void)out_size; (void)ws_size;
    const float* x      = (const float*)d_in[0];
    const float* weight = (const float*)d_in[1];
    const float* bias   = (const float*)d_in[2];
    const float* om_w   = (const float*)d_in[3];
    const float* om_b   = (const float*)d_in[4];
    float* out = (float*)d_out;
    float* ws  = (float*)d_ws;

    float* wt2  = ws + WT2_OFF;
    float* wom2 = ws + WOM2_OFF;

    int prep_n = OO * CC * KK + NOM * CC * KK;  // 52416
    prep_kernel<<<(prep_n + 255) / 256, 256, 0, stream>>>(weight, om_w, wt2, wom2);

    int npix = BB * HWW;  // 65536
    fused_kernel<<<npix / 256, 256, 0, stream>>>(x, wt2, bias, wom2, om_b, out);
}

// Round 3
// 325.295 us; speedup vs baseline: 1.3473x; 1.3473x over previous
//
#include <hip/hip_runtime.h>
#include <math.h>

// Problem constants
#define BB 4
#define CC 64
#define HH 128
#define WW 128
#define OO 64
#define HWW (HH * WW)
#define KK 9
#define NOM 27

#define TP  64   // pixels per block tile (one row segment)
#define NCG 4    // channel/output groups (4 threads per pixel)
#define CPG 16   // channels per group

// ws layout (floats):
//   wt2  : [0,     36864)   [k][c][o]  9*64*64
//   wom2 : [36864, 52416)   [c][t][j]  64*9*27
#define WT2_OFF  0
#define WOM2_OFF 36864

// ---------------------------------------------------------------------------
__global__ void prep_kernel(const float* __restrict__ weight,     // (O,C,3,3)
                            const float* __restrict__ om_weight,  // (27,C,3,3)
                            float* __restrict__ wt2,              // (K,C,O)
                            float* __restrict__ wom2)             // (C,9,27)
{
    int d = blockIdx.x * 256 + threadIdx.x;
    if (d < OO * CC * KK) {
        // d = (k*64 + c)*64 + o
        int o = d & 63;
        int r = d >> 6;
        int c = r & 63;
        int k = r >> 6;
        wt2[d] = weight[(o * CC + c) * 9 + k];
    }
    int d2 = d - OO * CC * KK;
    if (d2 >= 0 && d2 < NOM * CC * KK) {
        // d2 = (c*9 + t)*27 + j
        int j  = d2 % 27;
        int ct = d2 / 27;
        int t  = ct % 9;
        int c  = ct / 9;
        wom2[d2] = om_weight[(j * CC + c) * 9 + t];
    }
}

// ---------------------------------------------------------------------------
// Block = 64-pixel row segment, 256 threads (4 channel/output groups x 64 pix).
// Phase A: om conv partials (each thread 16 channels) -> LDS reduce.
// Phase B: per-(pixel,tap) sampling weights/indices -> LDS (computed once).
// Phase C: per tap: stage V[c][pix] in LDS (each thread 16 ch gathers),
//          then GEMM: each thread 16 output channels over all 64 c.
__global__ void __launch_bounds__(256, 3)
fused_kernel(const float* __restrict__ x,     // (B,C,H,W)
             const float* __restrict__ wt2,   // (K,C,O)
             const float* __restrict__ bias,  // (O)
             const float* __restrict__ wom2,  // (C,9,27)
             const float* __restrict__ om_bias,
             float* __restrict__ out)         // (B,O,H,W)
{
    // ldsA: phase A partials [4][64][27] (27,648 B), reused as V[16][64][4] (16 KB)
    __shared__ float ldsA[NCG * TP * NOM];
    __shared__ float sw[4][KK * TP];   // bilinear corner weights (mask folded)
    __shared__ int   si[4][KK * TP];   // clamped corner indices (y*W+x)

    int t   = threadIdx.x;
    int pix = t & 63;
    int cg  = __builtin_amdgcn_readfirstlane(t >> 6);  // wave-uniform group id

    int bid = blockIdx.x;        // b*256 + ho*2 + (w0/64)
    int b   = bid >> 8;
    int r   = bid & 255;
    int ho  = r >> 1;
    int w0  = (r & 1) << 6;
    int wo  = w0 + pix;

    const float* xb = x + (size_t)b * CC * HWW;

    // ---------------- phase A: om conv partial (16 channels) ----------------
    float om[NOM];
#pragma unroll
    for (int j = 0; j < NOM; j++) om[j] = 0.f;

#pragma unroll 2
    for (int cc = 0; cc < CPG; cc++) {
        int c = cg * CPG + cc;
        const float* xc = xb + c * HWW;
        float v[9];
#pragma unroll
        for (int t9 = 0; t9 < 9; t9++) {
            int y  = ho + t9 / 3 - 1;
            int xw = wo + t9 % 3 - 1;
            bool ok = (y >= 0) & (y < HH) & (xw >= 0) & (xw < WW);
            v[t9] = ok ? xc[y * WW + xw] : 0.f;
        }
#pragma unroll
        for (int t9 = 0; t9 < 9; t9++) {
            const float* wr = wom2 + (c * 9 + t9) * NOM;  // wave-uniform row
#pragma unroll
            for (int j = 0; j < NOM; j++) om[j] += v[t9] * wr[j];
        }
    }
    {
        float* part = ldsA + (cg * TP + pix) * NOM;
#pragma unroll
        for (int j = 0; j < NOM; j++) part[j] = om[j];
    }
    __syncthreads();

    // ---------------- phase B: sampling precompute per (tap, pixel) ---------
    for (int item = t; item < KK * TP; item += 256) {
        int k  = item >> 6;
        int pp = item & 63;
        float oy = om_bias[k], ox = om_bias[9 + k], mz = om_bias[18 + k];
#pragma unroll
        for (int g = 0; g < NCG; g++) {
            const float* base = ldsA + (g * TP + pp) * NOM;
            oy += base[k]; ox += base[9 + k]; mz += base[18 + k];
        }
        float m = 1.f / (1.f + expf(-mz));

        int ky = k / 3, kx = k % 3;
        float py = oy + (float)(ho - 1 + ky);
        float px = ox + (float)(w0 + pp - 1 + kx);
        float fy0 = floorf(py), fx0 = floorf(px);
        float ly = py - fy0,  lx = px - fx0;
        int y0 = (int)fy0, x0i = (int)fx0;
        int y1 = y0 + 1,   x1i = x0i + 1;
        bool vy0 = (y0 >= 0) & (y0 < HH);
        bool vy1 = (y1 >= 0) & (y1 < HH);
        bool vx0 = (x0i >= 0) & (x0i < WW);
        bool vx1 = (x1i >= 0) & (x1i < WW);
        sw[0][item] = (vy0 & vx0) ? (1.f - ly) * (1.f - lx) * m : 0.f;
        sw[1][item] = (vy0 & vx1) ? (1.f - ly) * lx * m : 0.f;
        sw[2][item] = (vy1 & vx0) ? ly * (1.f - lx) * m : 0.f;
        sw[3][item] = (vy1 & vx1) ? ly * lx * m : 0.f;
        int cy0 = min(max(y0, 0), HH - 1), cy1 = min(max(y1, 0), HH - 1);
        int cx0 = min(max(x0i, 0), WW - 1), cx1 = min(max(x1i, 0), WW - 1);
        si[0][item] = cy0 * WW + cx0;
        si[1][item] = cy0 * WW + cx1;
        si[2][item] = cy1 * WW + cx0;
        si[3][item] = cy1 * WW + cx1;
    }
    __syncthreads();

    // ---------------- phase C: per tap, stage V then GEMM -------------------
    float acc[CPG];
#pragma unroll
    for (int o = 0; o < CPG; o++) acc[o] = 0.f;

    const float* xcg = xb + (cg * CPG) * HWW;

#pragma unroll 1
    for (int k = 0; k < KK; k++) {
        int idx = k * TP + pix;
        float w00 = sw[0][idx], w01 = sw[1][idx];
        float w10 = sw[2][idx], w11 = sw[3][idx];
        int i00 = si[0][idx], i01 = si[1][idx];
        int i10 = si[2][idx], i11 = si[3][idx];

        // stage V for this thread's 16 channels: V dword layout (c>>2,pix,c&3)
#pragma unroll
        for (int c4 = 0; c4 < 4; c4++) {
            float4 vv;
            float* vp = (float*)&vv;
#pragma unroll
            for (int j = 0; j < 4; j++) {
                const float* xc = xcg + (c4 * 4 + j) * HWW;
                vp[j] = w00 * xc[i00] + w01 * xc[i01]
                      + w10 * xc[i10] + w11 * xc[i11];
            }
            *(float4*)&ldsA[((cg * 4 + c4) * TP + pix) * 4] = vv;
        }
        __syncthreads();

        // GEMM: 64 c x 16 o; V via ds_read_b128, weights via s_load
#pragma unroll 4
        for (int c4 = 0; c4 < 16; c4++) {
            float4 vv = *(const float4*)&ldsA[(c4 * TP + pix) * 4];
            const float* vp = (const float*)&vv;
#pragma unroll
            for (int j = 0; j < 4; j++) {
                const float* wr = wt2 + (k * CC + c4 * 4 + j) * OO + cg * CPG;
#pragma unroll
                for (int o = 0; o < CPG; o++) acc[o] += vp[j] * wr[o];
            }
        }
        __syncthreads();
    }

    // ---------------- epilogue ----------------
#pragma unroll
    for (int o = 0; o < CPG; o++) {
        int oc = cg * CPG + o;
        out[((size_t)(b * OO + oc)) * HWW + ho * WW + wo] = acc[o] + bias[oc];
    }
}

// ---------------------------------------------------------------------------
extern "C" void kernel_launch(void* const* d_in, const int* in_sizes, int n_in,
                              void* d_out, int out_size, void* d_ws, size_t ws_size,
                              hipStream_t stream)
{
    (void)in_sizes; (void)n_in; (void)out_size; (void)ws_size;
    const float* x      = (const float*)d_in[0];
    const float* weight = (const float*)d_in[1];
    const float* bias   = (const float*)d_in[2];
    const float* om_w   = (const float*)d_in[3];
    const float* om_b   = (const float*)d_in[4];
    float* out = (float*)d_out;
    float* ws  = (float*)d_ws;

    float* wt2  = ws + WT2_OFF;
    float* wom2 = ws + WOM2_OFF;

    int prep_n = OO * CC * KK + NOM * CC * KK;  // 52416
    prep_kernel<<<(prep_n + 255) / 256, 256, 0, stream>>>(weight, om_w, wt2, wom2);

    int nblk = BB * HH * (WW / TP);  // 1024
    fused_kernel<<<nblk, 256, 0, stream>>>(x, wt2, bias, wom2, om_b, out);
}

// Round 4
// 201.005 us; speedup vs baseline: 2.1804x; 1.6183x over previous
//
#include <hip/hip_runtime.h>
#include <math.h>

#define BB 4
#define CC 64
#define HH 128
#define WW 128
#define OO 64
#define HWW (HH * WW)
#define KK 9
#define NCHUNK 18      // K = 576 = 18 chunks of 32 (tap-major: chunk = tap*2 + half)

typedef short bf8 __attribute__((ext_vector_type(8)));     // 8 bf16 bit patterns
typedef float f32x4 __attribute__((ext_vector_type(4)));

// ws byte offsets
#define WHF_OFF   0              // main W hi frags: 18*4*64*8 shorts = 73728 B
#define WLF_OFF   73728          // main W lo frags
#define WOMH_OFF  147456         // om W hi frags: 18*2*64*8 shorts = 36864 B
#define WOML_OFF  184320         // om W lo frags
#define OMOUT_OFF 221184         // om planes: 4*27*16384 fp32 = 7077888 B

__device__ inline unsigned short f2bf(float f) {
    union { float f; unsigned u; } x; x.f = f;
    unsigned u = x.u;
    return (unsigned short)((u + 0x7FFFu + ((u >> 16) & 1u)) >> 16);  // RNE
}
__device__ inline float bf2f(unsigned short h) {
    union { unsigned u; float f; } x; x.u = ((unsigned)h) << 16;
    return x.f;
}

// ---------------------------------------------------------------------------
// prep: split weights to bf16 hi/lo and lay out in exact A-fragment order:
//   frag[chunk][og][lane][j] = W[o = og*16 + (lane&15)][k = (lane>>4)*8 + j]
// where K = tap*64 + c, chunk covers K in [32*chunk, 32*chunk+32).
__global__ void prep_kernel(const float* __restrict__ weight,     // (O,C,3,3)
                            const float* __restrict__ om_weight,  // (27,C,3,3)
                            unsigned short* __restrict__ whf,
                            unsigned short* __restrict__ wlf,
                            unsigned short* __restrict__ womh,
                            unsigned short* __restrict__ woml)
{
    int d = blockIdx.x * 256 + threadIdx.x;
    if (d < 18 * 4 * 64 * 8) {
        int j = d & 7;
        int l = (d >> 3) & 63;
        int g = (d >> 9) & 3;   // og
        int t = d >> 11;        // chunk
        int o = g * 16 + (l & 15);
        int kk = (l >> 4) * 8 + j;
        int tap = t >> 1;
        int c = (t & 1) * 32 + kk;
        float w = weight[(o * CC + c) * 9 + tap];
        unsigned short h = f2bf(w);
        whf[d] = h;
        wlf[d] = f2bf(w - bf2f(h));
    }
    int d2 = d - 18 * 4 * 64 * 8;
    if (d2 >= 0 && d2 < 18 * 2 * 64 * 8) {
        int j = d2 & 7;
        int l = (d2 >> 3) & 63;
        int g = (d2 >> 9) & 1;  // og (M=32 padded from 27)
        int t = d2 >> 10;       // chunk
        int o = g * 16 + (l & 15);
        int kk = (l >> 4) * 8 + j;
        int tap = t >> 1;
        int c = (t & 1) * 32 + kk;
        float w = (o < 27) ? om_weight[(o * CC + c) * 9 + tap] : 0.f;
        unsigned short h = f2bf(w);
        womh[d2] = h;
        woml[d2] = f2bf(w - bf2f(h));
    }
}

// ---------------------------------------------------------------------------
// om conv via MFMA. Block = 64-pixel row segment, 256 threads (4 waves).
// M=32 (27 om channels + pad), K=576, N=64 pixels.
// Writes om planes (bias added; sigmoid applied to mask channels) to ws.
__global__ void __launch_bounds__(256, 4)
om_mfma(const float* __restrict__ x,
        const unsigned short* __restrict__ womh,
        const unsigned short* __restrict__ woml,
        const float* __restrict__ om_bias,
        float* __restrict__ omout)         // (B, 27, H, W)
{
    __shared__ __align__(16) short vh[64 * 40];
    __shared__ __align__(16) short vl[64 * 40];

    int t    = threadIdx.x;
    int lane = t & 63;
    int wv   = t >> 6;
    int pix  = t & 63;
    int cg   = t >> 6;

    int bid = blockIdx.x;       // b*256 + ho*2 + (w0>>6)
    int b   = bid >> 8;
    int r   = bid & 255;
    int ho  = r >> 1;
    int w0  = (r & 1) << 6;
    int wo  = w0 + pix;

    const float* xb = x + (size_t)b * CC * HWW;

    int og = wv >> 1;           // output group (0..1), M=32
    int sb = (wv & 1) * 2;      // pixel-subtile base (2 subtiles per wave)

    f32x4 acc[2];
    acc[0] = (f32x4){0.f, 0.f, 0.f, 0.f};
    acc[1] = (f32x4){0.f, 0.f, 0.f, 0.f};

#pragma unroll 1
    for (int ch = 0; ch < NCHUNK; ch++) {
        int tap = ch >> 1;
        int c0  = (ch & 1) * 32 + cg * 8;
        int dy = tap / 3 - 1, dx = tap % 3 - 1;
        int y = ho + dy, xw = wo + dx;
        bool ok = (y >= 0) & (y < HH) & (xw >= 0) & (xw < WW);
        int idx = ok ? (y * WW + xw) : 0;
        float zm = ok ? 1.f : 0.f;

        bf8 hv, lv;
#pragma unroll
        for (int j = 0; j < 8; j++) {
            float v = xb[(size_t)(c0 + j) * HWW + idx] * zm;
            unsigned short hh = f2bf(v);
            hv[j] = (short)hh;
            lv[j] = (short)f2bf(v - bf2f(hh));
        }
        __syncthreads();   // previous chunk's B-fragment reads done
        *(bf8*)&vh[pix * 40 + cg * 8] = hv;
        *(bf8*)&vl[pix * 40 + cg * 8] = lv;
        __syncthreads();

        bf8 a_h = *(const bf8*)&womh[(size_t)((ch * 2 + og) * 64 + lane) * 8];
        bf8 a_l = *(const bf8*)&woml[(size_t)((ch * 2 + og) * 64 + lane) * 8];
#pragma unroll
        for (int s = 0; s < 2; s++) {
            int pr = (sb + s) * 16 + (lane & 15);
            bf8 b_h = *(const bf8*)&vh[pr * 40 + (lane >> 4) * 8];
            bf8 b_l = *(const bf8*)&vl[pr * 40 + (lane >> 4) * 8];
            acc[s] = __builtin_amdgcn_mfma_f32_16x16x32_bf16(a_h, b_h, acc[s], 0, 0, 0);
            acc[s] = __builtin_amdgcn_mfma_f32_16x16x32_bf16(a_h, b_l, acc[s], 0, 0, 0);
            acc[s] = __builtin_amdgcn_mfma_f32_16x16x32_bf16(a_l, b_h, acc[s], 0, 0, 0);
        }
    }

    // epilogue: C/D col=lane&15 (pixel), row=(lane>>4)*4+reg (om channel)
#pragma unroll
    for (int s = 0; s < 2; s++) {
#pragma unroll
        for (int rg = 0; rg < 4; rg++) {
            int m = og * 16 + (lane >> 4) * 4 + rg;
            if (m < 27) {
                int pp = (sb + s) * 16 + (lane & 15);
                float v = acc[s][rg] + om_bias[m];
                if (m >= 18) v = 1.f / (1.f + expf(-v));
                omout[((size_t)(b * 27 + m)) * HWW + ho * WW + w0 + pp] = v;
            }
        }
    }
}

// ---------------------------------------------------------------------------
// Main deformable conv via MFMA. Block = 64-pixel row segment, 256 threads.
// M=64 outputs (wave og = wave id), K=576, N=64 pixels (4 subtiles of 16).
__global__ void __launch_bounds__(256, 4)
main_mfma(const float* __restrict__ x,
          const unsigned short* __restrict__ whf,
          const unsigned short* __restrict__ wlf,
          const float* __restrict__ bias,
          const float* __restrict__ omout,
          float* __restrict__ out)         // (B,O,H,W)
{
    __shared__ __align__(16) short vh[64 * 40];
    __shared__ __align__(16) short vl[64 * 40];
    __shared__ float sw[4][KK * 64];
    __shared__ int   si[4][KK * 64];

    int t    = threadIdx.x;
    int lane = t & 63;
    int wv   = t >> 6;
    int pix  = t & 63;
    int cg   = t >> 6;

    int bid = blockIdx.x;
    int b   = bid >> 8;
    int r   = bid & 255;
    int ho  = r >> 1;
    int w0  = (r & 1) << 6;

    const float* xb  = x + (size_t)b * CC * HWW;
    const float* omb = omout + (size_t)b * 27 * HWW;
    int prow = ho * WW + w0;

    // ---------------- phase B: sampling params per (tap, pixel) ----------
    for (int item = t; item < KK * 64; item += 256) {
        int k  = item >> 6;
        int pp = item & 63;
        float oy = omb[(size_t)k * HWW + prow + pp];
        float ox = omb[(size_t)(9 + k) * HWW + prow + pp];
        float m  = omb[(size_t)(18 + k) * HWW + prow + pp];  // sigmoided

        int ky = k / 3, kx = k % 3;
        float py = oy + (float)(ho - 1 + ky);
        float px = ox + (float)(w0 + pp - 1 + kx);
        float fy0 = floorf(py), fx0 = floorf(px);
        float ly = py - fy0, lx = px - fx0;
        int y0 = (int)fy0, x0i = (int)fx0;
        int y1 = y0 + 1,   x1i = x0i + 1;
        bool vy0 = (y0 >= 0) & (y0 < HH);
        bool vy1 = (y1 >= 0) & (y1 < HH);
        bool vx0 = (x0i >= 0) & (x0i < WW);
        bool vx1 = (x1i >= 0) & (x1i < WW);
        sw[0][item] = (vy0 & vx0) ? (1.f - ly) * (1.f - lx) * m : 0.f;
        sw[1][item] = (vy0 & vx1) ? (1.f - ly) * lx * m : 0.f;
        sw[2][item] = (vy1 & vx0) ? ly * (1.f - lx) * m : 0.f;
        sw[3][item] = (vy1 & vx1) ? ly * lx * m : 0.f;
        int cy0 = min(max(y0, 0), HH - 1), cy1 = min(max(y1, 0), HH - 1);
        int cx0 = min(max(x0i, 0), WW - 1), cx1 = min(max(x1i, 0), WW - 1);
        si[0][item] = cy0 * WW + cx0;
        si[1][item] = cy0 * WW + cx1;
        si[2][item] = cy1 * WW + cx0;
        si[3][item] = cy1 * WW + cx1;
    }

    f32x4 acc[4];
#pragma unroll
    for (int s = 0; s < 4; s++) acc[s] = (f32x4){0.f, 0.f, 0.f, 0.f};

    __syncthreads();

    // ---------------- main loop: gather -> LDS -> MFMA --------------------
#pragma unroll 1
    for (int ch = 0; ch < NCHUNK; ch++) {
        int tap = ch >> 1;
        int c0  = (ch & 1) * 32 + cg * 8;
        int it  = tap * 64 + pix;
        float w00 = sw[0][it], w01 = sw[1][it];
        float w10 = sw[2][it], w11 = sw[3][it];
        int i00 = si[0][it], i01 = si[1][it];
        int i10 = si[2][it], i11 = si[3][it];

        const float* xc = xb + (size_t)c0 * HWW;
        bf8 hv, lv;
#pragma unroll
        for (int j = 0; j < 8; j++) {
            const float* xcc = xc + (size_t)j * HWW;
            float v = w00 * xcc[i00] + w01 * xcc[i01]
                    + w10 * xcc[i10] + w11 * xcc[i11];
            unsigned short hh = f2bf(v);
            hv[j] = (short)hh;
            lv[j] = (short)f2bf(v - bf2f(hh));
        }
        __syncthreads();   // previous chunk's B-fragment reads done
        *(bf8*)&vh[pix * 40 + cg * 8] = hv;
        *(bf8*)&vl[pix * 40 + cg * 8] = lv;
        __syncthreads();

        bf8 a_h = *(const bf8*)&whf[(size_t)((ch * 4 + wv) * 64 + lane) * 8];
        bf8 a_l = *(const bf8*)&wlf[(size_t)((ch * 4 + wv) * 64 + lane) * 8];
#pragma unroll
        for (int s = 0; s < 4; s++) {
            int pr = s * 16 + (lane & 15);
            bf8 b_h = *(const bf8*)&vh[pr * 40 + (lane >> 4) * 8];
            bf8 b_l = *(const bf8*)&vl[pr * 40 + (lane >> 4) * 8];
            acc[s] = __builtin_amdgcn_mfma_f32_16x16x32_bf16(a_h, b_h, acc[s], 0, 0, 0);
            acc[s] = __builtin_amdgcn_mfma_f32_16x16x32_bf16(a_h, b_l, acc[s], 0, 0, 0);
            acc[s] = __builtin_amdgcn_mfma_f32_16x16x32_bf16(a_l, b_h, acc[s], 0, 0, 0);
        }
    }

    // ---------------- epilogue ----------------
#pragma unroll
    for (int s = 0; s < 4; s++) {
#pragma unroll
        for (int rg = 0; rg < 4; rg++) {
            int o  = wv * 16 + (lane >> 4) * 4 + rg;
            int pp = s * 16 + (lane & 15);
            out[((size_t)(b * OO + o)) * HWW + prow + pp] = acc[s][rg] + bias[o];
        }
    }
}

// ---------------------------------------------------------------------------
extern "C" void kernel_launch(void* const* d_in, const int* in_sizes, int n_in,
                              void* d_out, int out_size, void* d_ws, size_t ws_size,
                              hipStream_t stream)
{
    (void)in_sizes; (void)n_in; (void)out_size; (void)ws_size;
    const float* x      = (const float*)d_in[0];
    const float* weight = (const float*)d_in[1];
    const float* bias   = (const float*)d_in[2];
    const float* om_w   = (const float*)d_in[3];
    const float* om_b   = (const float*)d_in[4];
    float* out = (float*)d_out;
    char*  ws  = (char*)d_ws;

    unsigned short* whf  = (unsigned short*)(ws + WHF_OFF);
    unsigned short* wlf  = (unsigned short*)(ws + WLF_OFF);
    unsigned short* womh = (unsigned short*)(ws + WOMH_OFF);
    unsigned short* woml = (unsigned short*)(ws + WOML_OFF);
    float*          omo  = (float*)(ws + OMOUT_OFF);

    int prep_n = 18 * 4 * 64 * 8 + 18 * 2 * 64 * 8;  // 55296
    prep_kernel<<<(prep_n + 255) / 256, 256, 0, stream>>>(weight, om_w, whf, wlf, womh, woml);

    int nblk = BB * HH * (WW / 64);  // 1024
    om_mfma<<<nblk, 256, 0, stream>>>(x, womh, woml, om_b, omo);
    main_mfma<<<nblk, 256, 0, stream>>>(x, whf, wlf, bias, omo, out);
}

// Round 5
// 160.352 us; speedup vs baseline: 2.7332x; 1.2535x over previous
//
#include <hip/hip_runtime.h>
#include <math.h>

#define BB 4
#define CC 64
#define HH 128
#define WW 128
#define OO 64
#define HWW (HH * WW)

typedef short bf8 __attribute__((ext_vector_type(8)));
typedef float f32x4 __attribute__((ext_vector_type(4)));

// ws byte offsets (weight fragments only, ~216 KB)
#define WHF_OFF  0          // main W hi frags: 18*4*64*8 shorts = 73728 B
#define WLF_OFF  73728      // main W lo frags
#define WOMH_OFF 147456     // om W hi frags: 18*2*64*8 shorts = 36864 B
#define WOML_OFF 184320     // om W lo frags

__device__ inline unsigned short f2bf(float f) {
    union { float f; unsigned u; } x; x.f = f;
    unsigned u = x.u;
    return (unsigned short)((u + 0x7FFFu + ((u >> 16) & 1u)) >> 16);  // RNE
}
__device__ inline float bf2f(unsigned short h) {
    union { unsigned u; float f; } x; x.u = ((unsigned)h) << 16;
    return x.f;
}

// ---------------------------------------------------------------------------
// prep: weights -> bf16 hi/lo A-fragments.
// chunk = half*9 + tap covers channels [half*32, half*32+32) of tap.
// A-frag: lane l holds W[o = grp*16 + (l&15)][k = (l>>4)*8 + j].
__global__ void prep_kernel(const float* __restrict__ weight,     // (O,C,3,3)
                            const float* __restrict__ om_weight,  // (27,C,3,3)
                            unsigned short* __restrict__ whf,
                            unsigned short* __restrict__ wlf,
                            unsigned short* __restrict__ womh,
                            unsigned short* __restrict__ woml)
{
    int d = blockIdx.x * 256 + threadIdx.x;
    if (d < 18 * 4 * 64 * 8) {
        int j  = d & 7;
        int l  = (d >> 3) & 63;
        int wv = (d >> 9) & 3;
        int ch = d >> 11;          // 0..17
        int o  = wv * 16 + (l & 15);
        int kk = (l >> 4) * 8 + j;
        int c  = (ch / 9) * 32 + kk;
        int tap = ch % 9;
        float w = weight[(o * CC + c) * 9 + tap];
        unsigned short h = f2bf(w);
        whf[d] = h;
        wlf[d] = f2bf(w - bf2f(h));
    }
    int d2 = d - 18 * 4 * 64 * 8;
    if (d2 >= 0 && d2 < 18 * 2 * 64 * 8) {
        int j  = d2 & 7;
        int l  = (d2 >> 3) & 63;
        int og = (d2 >> 9) & 1;
        int ch = d2 >> 10;         // 0..17
        int o  = og * 16 + (l & 15);
        int kk = (l >> 4) * 8 + j;
        int c  = (ch / 9) * 32 + kk;
        int tap = ch % 9;
        float w = (o < 27) ? om_weight[(o * CC + c) * 9 + tap] : 0.f;
        unsigned short h = f2bf(w);
        womh[d2] = h;
        woml[d2] = f2bf(w - bf2f(h));
    }
}

// ---------------------------------------------------------------------------
// Fused kernel. Block = 32-pixel row segment, 256 threads (4 waves).
// x window (5 rows x 36 cols, clamp-filled halo) staged in LDS per 32-ch half;
// om conv + bilinear gathers all served from LDS.
__global__ void __launch_bounds__(256, 4)
fused_kernel(const float* __restrict__ x,     // (B,C,H,W)
             const unsigned short* __restrict__ whf,
             const unsigned short* __restrict__ wlf,
             const unsigned short* __restrict__ womh,
             const unsigned short* __restrict__ woml,
             const float* __restrict__ bias,
             const float* __restrict__ om_bias,
             float* __restrict__ out)         // (B,O,H,W)
{
    // Xs: [32 ch][5 rows][36 cols], c-stride padded to 182 (bank spread) = 23,296 B
    __shared__ float Xs[32 * 182];
    // fragment double-buffers: [buf][pix 32][20 uints = 40 shorts(32+pad8)] = 5,120 B each
    __shared__ unsigned vh[2][32][20];
    __shared__ unsigned vl[2][32][20];
    __shared__ float swt[4][288];   // bilinear corner weights (mask+validity folded)
    __shared__ int   sidx[288];     // packed (y0,x0) + escape flag (bit 31)

    int t    = threadIdx.x;
    int lane = t & 63;
    int wv   = t >> 6;

    int bid = blockIdx.x;           // b*512 + ho*4 + q
    int b   = bid >> 9;
    int r   = bid & 511;
    int ho  = r >> 2;
    int w0  = (r & 3) << 5;

    // ---------------- stage: x half-window -> LDS (coalesced) ----------------
    auto stage = [&](int half) {
        const float* xh = x + ((size_t)(b * CC + half * 32)) * HWW;
#pragma unroll 1
        for (int i = t; i < 32 * 180; i += 256) {
            int c   = i / 180;
            int rem = i - c * 180;
            int rr  = rem / 36;
            int cc  = rem - rr * 36;
            int gy = min(max(ho - 2 + rr, 0), HH - 1);
            int gx = min(max(w0 - 2 + cc, 0), WW - 1);
            Xs[c * 182 + rem] = xh[(size_t)c * HWW + gy * WW + gx];
        }
    };

    // ---------------- om conv: B-frags direct from Xs, no barriers ----------
    f32x4 accom = (f32x4){0.f, 0.f, 0.f, 0.f};
    auto om_pass = [&](int half) {
        int og = wv & 1;
        int s  = wv >> 1;
        int pix_s = s * 16 + (lane & 15);
        int kk0   = (lane >> 4) * 8;
#pragma unroll 1
        for (int tap = 0; tap < 9; tap++) {
            int ch = half * 9 + tap;
            int ky = tap / 3, kx = tap - ky * 3;
            int y  = ho + ky - 1;
            int xw = w0 + pix_s + kx - 1;
            bool okv = (y >= 0) & (y < HH) & (xw >= 0) & (xw < WW);  // zero-pad conv
            float zm = okv ? 1.f : 0.f;
            const float* Xp = &Xs[kk0 * 182 + (ky + 1) * 36 + (pix_s + kx + 1)];
            bf8 bh, bl;
#pragma unroll
            for (int j = 0; j < 8; j++) {
                float v = Xp[j * 182] * zm;
                unsigned short hh = f2bf(v);
                bh[j] = (short)hh;
                bl[j] = (short)f2bf(v - bf2f(hh));
            }
            const bf8 ah = *(const bf8*)&womh[((size_t)(ch * 2 + og) * 64 + lane) * 8];
            const bf8 al = *(const bf8*)&woml[((size_t)(ch * 2 + og) * 64 + lane) * 8];
            accom = __builtin_amdgcn_mfma_f32_16x16x32_bf16(ah, bh, accom, 0, 0, 0);
            accom = __builtin_amdgcn_mfma_f32_16x16x32_bf16(ah, bl, accom, 0, 0, 0);
            accom = __builtin_amdgcn_mfma_f32_16x16x32_bf16(al, bh, accom, 0, 0, 0);
        }
    };

    // ---------------- main conv half-pass ----------------
    f32x4 acc[2];
    acc[0] = (f32x4){0.f, 0.f, 0.f, 0.f};
    acc[1] = (f32x4){0.f, 0.f, 0.f, 0.f};

    auto main_pass = [&](int half) {
        int pix = t & 31;
        int cg  = t >> 5;           // 0..7, 4 channels each
        const float* xg = x + ((size_t)(b * CC + half * 32 + cg * 4)) * HWW;
#pragma unroll 1
        for (int tap = 0; tap < 9; tap++) {
            int ach  = half * 9 + tap;
            int buf  = tap & 1;
            int item = tap * 32 + pix;
            float w00 = swt[0][item], w01 = swt[1][item];
            float w10 = swt[2][item], w11 = swt[3][item];
            int sv = sidx[item];
            int y0 = ((sv >> 16) & 0x7FFF) - 16;
            int x0 = (sv & 0xFFFF) - 16;
            // prefetch A fragments (L2-resident)
            const bf8 ah = *(const bf8*)&whf[((size_t)(ach * 4 + wv) * 64 + lane) * 8];
            const bf8 al = *(const bf8*)&wlf[((size_t)(ach * 4 + wv) * 64 + lane) * 8];

            float v[4];
            if (sv >= 0) {
                // in-window: unclamped virtual coords over clamp-filled halo
                int o00 = (y0 - ho + 2) * 36 + (x0 - w0 + 2);
                const float* Xp = &Xs[cg * 4 * 182 + o00];
#pragma unroll
                for (int j = 0; j < 4; j++) {
                    float a0 = Xp[j * 182],      a1 = Xp[j * 182 + 1];
                    float b0 = Xp[j * 182 + 36], b1 = Xp[j * 182 + 37];
                    v[j] = w00 * a0 + w01 * a1 + w10 * b0 + w11 * b1;
                }
            } else {
                // rare escape: clamped global gather (always correct)
                int cy0 = min(max(y0, 0), HH - 1), cy1 = min(max(y0 + 1, 0), HH - 1);
                int cx0 = min(max(x0, 0), WW - 1), cx1 = min(max(x0 + 1, 0), WW - 1);
                int i00 = cy0 * WW + cx0, i01 = cy0 * WW + cx1;
                int i10 = cy1 * WW + cx0, i11 = cy1 * WW + cx1;
#pragma unroll
                for (int j = 0; j < 4; j++) {
                    const float* xc = xg + (size_t)j * HWW;
                    v[j] = w00 * xc[i00] + w01 * xc[i01]
                         + w10 * xc[i10] + w11 * xc[i11];
                }
            }
            // hi/lo split, pack, store fragment slice
            unsigned hh0 = f2bf(v[0]), hh1 = f2bf(v[1]);
            unsigned hh2 = f2bf(v[2]), hh3 = f2bf(v[3]);
            unsigned ll0 = f2bf(v[0] - bf2f((unsigned short)hh0));
            unsigned ll1 = f2bf(v[1] - bf2f((unsigned short)hh1));
            unsigned ll2 = f2bf(v[2] - bf2f((unsigned short)hh2));
            unsigned ll3 = f2bf(v[3] - bf2f((unsigned short)hh3));
            uint2 hw, lw;
            hw.x = hh0 | (hh1 << 16); hw.y = hh2 | (hh3 << 16);
            lw.x = ll0 | (ll1 << 16); lw.y = ll2 | (ll3 << 16);
            *(uint2*)&vh[buf][pix][cg * 2] = hw;
            *(uint2*)&vl[buf][pix][cg * 2] = lw;
            __syncthreads();
#pragma unroll
            for (int s = 0; s < 2; s++) {
                const bf8 bh = *(const bf8*)&vh[buf][s * 16 + (lane & 15)][(lane >> 4) * 4];
                const bf8 bl = *(const bf8*)&vl[buf][s * 16 + (lane & 15)][(lane >> 4) * 4];
                acc[s] = __builtin_amdgcn_mfma_f32_16x16x32_bf16(ah, bh, acc[s], 0, 0, 0);
                acc[s] = __builtin_amdgcn_mfma_f32_16x16x32_bf16(ah, bl, acc[s], 0, 0, 0);
                acc[s] = __builtin_amdgcn_mfma_f32_16x16x32_bf16(al, bh, acc[s], 0, 0, 0);
            }
        }
    };

    // =========================== block timeline ===========================
    stage(1);
    __syncthreads();
    om_pass(1);
    __syncthreads();          // Xs(half1) reads done
    stage(0);
    __syncthreads();
    om_pass(0);

    // om epilogue -> omL (union with vh region; vh unused until main loop)
    float* omL = (float*)&vh[0][0][0];   // 28*32 floats = 3,584 B < 10,240 B
    {
        int og = wv & 1, s = wv >> 1;
#pragma unroll
        for (int rg = 0; rg < 4; rg++) {
            int m = og * 16 + (lane >> 4) * 4 + rg;
            if (m < 27) {
                int pp = s * 16 + (lane & 15);
                float v = accom[rg] + om_bias[m];
                if (m >= 18) v = 1.f / (1.f + expf(-v));
                omL[m * 32 + pp] = v;
            }
        }
    }
    __syncthreads();

    // phase B: sampling params per (tap, pixel)
#pragma unroll 1
    for (int it = t; it < 288; it += 256) {
        int k  = it >> 5;
        int pp = it & 31;
        float oy = omL[k * 32 + pp];
        float ox = omL[(9 + k) * 32 + pp];
        float mm = omL[(18 + k) * 32 + pp];
        int ky = k / 3, kx = k - ky * 3;
        float py = oy + (float)(ho + ky - 1);
        float px = ox + (float)(w0 + pp + kx - 1);
        float fy = floorf(py), fx = floorf(px);
        float ly = py - fy, lx = px - fx;
        int y0 = (int)fy, x0 = (int)fx;
        bool vy0 = (y0 >= 0) & (y0 < HH);
        bool vy1 = (y0 + 1 >= 0) & (y0 + 1 < HH);
        bool vx0 = (x0 >= 0) & (x0 < WW);
        bool vx1 = (x0 + 1 >= 0) & (x0 + 1 < WW);
        swt[0][it] = (vy0 & vx0) ? (1.f - ly) * (1.f - lx) * mm : 0.f;
        swt[1][it] = (vy0 & vx1) ? (1.f - ly) * lx * mm : 0.f;
        swt[2][it] = (vy1 & vx0) ? ly * (1.f - lx) * mm : 0.f;
        swt[3][it] = (vy1 & vx1) ? ly * lx * mm : 0.f;
        bool inw = (y0 >= ho - 2) & (y0 <= ho + 1) & (x0 >= w0 - 2) & (x0 <= w0 + 32);
        // clamp coords for encode; far-out coords have all-zero weights anyway
        int y0c = min(max(y0, -8), 135);
        int x0c = min(max(x0, -8), 135);
        sidx[it] = ((y0c + 16) << 16) | ((x0c + 16) & 0xFFFF)
                 | (inw ? 0 : (int)0x80000000);
    }
    __syncthreads();

    main_pass(0);             // Xs currently holds half 0
    stage(1);                 // safe: all Xs reads done at last chunk barrier
    __syncthreads();
    main_pass(1);

    // epilogue
    int prow = ho * WW + w0;
#pragma unroll
    for (int s = 0; s < 2; s++) {
#pragma unroll
        for (int rg = 0; rg < 4; rg++) {
            int o  = wv * 16 + (lane >> 4) * 4 + rg;
            int pp = s * 16 + (lane & 15);
            out[((size_t)(b * OO + o)) * HWW + prow + pp] = acc[s][rg] + bias[o];
        }
    }
}

// ---------------------------------------------------------------------------
extern "C" void kernel_launch(void* const* d_in, const int* in_sizes, int n_in,
                              void* d_out, int out_size, void* d_ws, size_t ws_size,
                              hipStream_t stream)
{
    (void)in_sizes; (void)n_in; (void)out_size; (void)ws_size;
    const float* x      = (const float*)d_in[0];
    const float* weight = (const float*)d_in[1];
    const float* bias   = (const float*)d_in[2];
    const float* om_w   = (const float*)d_in[3];
    const float* om_b   = (const float*)d_in[4];
    float* out = (float*)d_out;
    char*  ws  = (char*)d_ws;

    unsigned short* whf  = (unsigned short*)(ws + WHF_OFF);
    unsigned short* wlf  = (unsigned short*)(ws + WLF_OFF);
    unsigned short* womh = (unsigned short*)(ws + WOMH_OFF);
    unsigned short* woml = (unsigned short*)(ws + WOML_OFF);

    int prep_n = 18 * 4 * 64 * 8 + 18 * 2 * 64 * 8;  // 55296
    prep_kernel<<<(prep_n + 255) / 256, 256, 0, stream>>>(weight, om_w, whf, wlf, womh, woml);

    int nblk = BB * HH * (WW / 32);  // 2048
    fused_kernel<<<nblk, 256, 0, stream>>>(x, whf, wlf, womh, woml, bias, om_b, out);
}

// Round 6
// 133.855 us; speedup vs baseline: 3.2742x; 1.1979x over previous
//
#include <hip/hip_runtime.h>
#include <math.h>

#define BB 4
#define CC 64
#define HH 128
#define WW 128
#define OO 64
#define HWW (HH * WW)

typedef short bf8 __attribute__((ext_vector_type(8)));
typedef float f32x4 __attribute__((ext_vector_type(4)));

// ws byte offsets (weight fragments only, ~216 KB)
#define WHF_OFF  0          // main W hi frags: 18*4*64*8 shorts = 73728 B
#define WLF_OFF  73728      // main W lo frags
#define WOMH_OFF 147456     // om W hi frags: 18*2*64*8 shorts = 36864 B
#define WOML_OFF 184320     // om W lo frags

__device__ inline unsigned short f2bf(float f) {           // RNE (prep only)
    union { float f; unsigned u; } x; x.f = f;
    unsigned u = x.u;
    return (unsigned short)((u + 0x7FFFu + ((u >> 16) & 1u)) >> 16);
}
__device__ inline float bf2f(unsigned short h) {
    union { unsigned u; float f; } x; x.u = ((unsigned)h) << 16;
    return x.f;
}
// pack truncated-bf16 of (a,b) into one uint: lo16 = bf(a), hi16 = bf(b)
__device__ inline unsigned pack_hi2(float a, float b) {
    return (__float_as_uint(a) >> 16) | (__float_as_uint(b) & 0xFFFF0000u);
}

// ---------------------------------------------------------------------------
// prep: weights -> bf16 hi/lo A-fragments (RNE split, done once).
// chunk ch = half*9 + tap covers channels [half*32, half*32+32) of tap.
// A-frag: lane l holds W[o = grp*16 + (l&15)][k = (l>>4)*8 + j].
__global__ void prep_kernel(const float* __restrict__ weight,     // (O,C,3,3)
                            const float* __restrict__ om_weight,  // (27,C,3,3)
                            unsigned short* __restrict__ whf,
                            unsigned short* __restrict__ wlf,
                            unsigned short* __restrict__ womh,
                            unsigned short* __restrict__ woml)
{
    int d = blockIdx.x * 256 + threadIdx.x;
    if (d < 18 * 4 * 64 * 8) {
        int j  = d & 7;
        int l  = (d >> 3) & 63;
        int wv = (d >> 9) & 3;
        int ch = d >> 11;
        int o  = wv * 16 + (l & 15);
        int kk = (l >> 4) * 8 + j;
        int c  = (ch / 9) * 32 + kk;
        int tap = ch % 9;
        float w = weight[(o * CC + c) * 9 + tap];
        unsigned short h = f2bf(w);
        whf[d] = h;
        wlf[d] = f2bf(w - bf2f(h));
    }
    int d2 = d - 18 * 4 * 64 * 8;
    if (d2 >= 0 && d2 < 18 * 2 * 64 * 8) {
        int j  = d2 & 7;
        int l  = (d2 >> 3) & 63;
        int og = (d2 >> 9) & 1;
        int ch = d2 >> 10;
        int o  = og * 16 + (l & 15);
        int kk = (l >> 4) * 8 + j;
        int c  = (ch / 9) * 32 + kk;
        int tap = ch % 9;
        float w = (o < 27) ? om_weight[(o * CC + c) * 9 + tap] : 0.f;
        unsigned short h = f2bf(w);
        womh[d2] = h;
        woml[d2] = f2bf(w - bf2f(h));
    }
}

// ---------------------------------------------------------------------------
// Fused kernel. Block = 32-pixel row segment, 256 threads (4 waves).
// x half-window (5 rows x 36 cols, ZERO-filled out-of-image halo) staged in
// LDS as [cg][pos][4ch] float4s; om frags + bilinear corners via ds_read_b128.
__global__ void __launch_bounds__(256, 4)
fused_kernel(const float* __restrict__ x,     // (B,C,H,W)
             const unsigned short* __restrict__ whf,
             const unsigned short* __restrict__ wlf,
             const unsigned short* __restrict__ womh,
             const unsigned short* __restrict__ woml,
             const float* __restrict__ bias,
             const float* __restrict__ om_bias,
             float* __restrict__ out)         // (B,O,H,W)
{
    __shared__ __align__(16) float Xs2[8 * 180 * 4];   // [cg][pos][j] 23,040 B
    __shared__ __align__(16) unsigned vhf[2][32][21];  // 5,376 B (pad 21: conflict-free)
    __shared__ __align__(16) unsigned vlf[2][32][21];  // 5,376 B
    __shared__ float swt[4][288];                      // 4,608 B
    __shared__ int   sidx[288];                        // 1,152 B  -> total 39,552 B

    int t    = threadIdx.x;
    int lane = t & 63;
    int wv   = t >> 6;

    int bid = blockIdx.x;           // b*512 + ho*4 + q
    int b   = bid >> 9;
    int r   = bid & 511;
    int ho  = r >> 2;
    int w0  = (r & 3) << 5;

    // ---------------- stage: x half-window -> LDS (zero halo) --------------
    auto stage = [&](int half) {
        const float* xh = x + ((size_t)(b * CC + half * 32)) * HWW;
#pragma unroll 1
        for (int i = t; i < 1440; i += 256) {          // cg*180 + pos
            int cg  = i / 180;
            int pos = i - cg * 180;
            int rr  = pos / 36;
            int cc2 = pos - rr * 36;
            int gy = ho - 2 + rr, gx = w0 - 2 + cc2;
            bool ok = (gy >= 0) & (gy < HH) & (gx >= 0) & (gx < WW);
            int gi = ok ? gy * WW + gx : 0;
            const float* xc = xh + (size_t)cg * 4 * HWW + gi;
            float4 v;
            v.x = xc[0]; v.y = xc[HWW]; v.z = xc[2 * HWW]; v.w = xc[3 * HWW];
            if (!ok) { v.x = 0.f; v.y = 0.f; v.z = 0.f; v.w = 0.f; }
            *(float4*)&Xs2[(cg * 180 + pos) * 4] = v;
        }
    };

    // ---------------- om conv: single-bf16 B (trunc), 2 MFMAs/tap ----------
    f32x4 accom = (f32x4){0.f, 0.f, 0.f, 0.f};
    auto om_pass = [&](int half) {
        int og = wv & 1;
        int s  = wv >> 1;
        int pix_s = s * 16 + (lane & 15);
        int cg0   = (lane >> 4) * 2;      // channels kk0..kk0+7 = cg0, cg0+1
#pragma unroll 1
        for (int tap = 0; tap < 9; tap++) {
            int ch = half * 9 + tap;
            int ky = tap / 3, kx = tap - ky * 3;
            int pos = (ky + 1) * 36 + pix_s + kx + 1;
            float4 f0 = *(const float4*)&Xs2[(cg0 * 180 + pos) * 4];
            float4 f1 = *(const float4*)&Xs2[((cg0 + 1) * 180 + pos) * 4];
            bf8 bh;
            ((unsigned*)&bh)[0] = pack_hi2(f0.x, f0.y);
            ((unsigned*)&bh)[1] = pack_hi2(f0.z, f0.w);
            ((unsigned*)&bh)[2] = pack_hi2(f1.x, f1.y);
            ((unsigned*)&bh)[3] = pack_hi2(f1.z, f1.w);
            const bf8 ah = *(const bf8*)&womh[((size_t)(ch * 2 + og) * 64 + lane) * 8];
            const bf8 al = *(const bf8*)&woml[((size_t)(ch * 2 + og) * 64 + lane) * 8];
            accom = __builtin_amdgcn_mfma_f32_16x16x32_bf16(ah, bh, accom, 0, 0, 0);
            accom = __builtin_amdgcn_mfma_f32_16x16x32_bf16(al, bh, accom, 0, 0, 0);
        }
    };

    // ---------------- main conv half-pass ----------------
    f32x4 acc[2];
    acc[0] = (f32x4){0.f, 0.f, 0.f, 0.f};
    acc[1] = (f32x4){0.f, 0.f, 0.f, 0.f};

    auto main_pass = [&](int half) {
        int pix = t & 31;
        int cg  = t >> 5;               // 0..7, 4 channels each
        const float* xg = x + ((size_t)(b * CC + half * 32 + cg * 4)) * HWW;
#pragma unroll 1
        for (int tap = 0; tap < 9; tap++) {
            int ach  = half * 9 + tap;
            int buf  = tap & 1;
            int item = tap * 32 + pix;
            float w00 = swt[0][item], w01 = swt[1][item];
            float w10 = swt[2][item], w11 = swt[3][item];
            int sv = sidx[item];
            int y0 = ((sv >> 16) & 0x7FFF) - 16;
            int x0 = (sv & 0xFFFF) - 16;
            const bf8 ah = *(const bf8*)&whf[((size_t)(ach * 4 + wv) * 64 + lane) * 8];
            const bf8 al = *(const bf8*)&wlf[((size_t)(ach * 4 + wv) * 64 + lane) * 8];

            float v0, v1, v2, v3;
            if (sv >= 0) {
                int o00 = (y0 - ho + 2) * 36 + (x0 - w0 + 2);
                const float* Xp = &Xs2[(cg * 180 + o00) * 4];
                float4 c00 = *(const float4*)(Xp);
                float4 c01 = *(const float4*)(Xp + 4);
                float4 c10 = *(const float4*)(Xp + 144);
                float4 c11 = *(const float4*)(Xp + 148);
                v0 = w00 * c00.x + w01 * c01.x + w10 * c10.x + w11 * c11.x;
                v1 = w00 * c00.y + w01 * c01.y + w10 * c10.y + w11 * c11.y;
                v2 = w00 * c00.z + w01 * c01.z + w10 * c10.z + w11 * c11.z;
                v3 = w00 * c00.w + w01 * c01.w + w10 * c10.w + w11 * c11.w;
            } else {
                int cy0 = min(max(y0, 0), HH - 1), cy1 = min(max(y0 + 1, 0), HH - 1);
                int cx0 = min(max(x0, 0), WW - 1), cx1 = min(max(x0 + 1, 0), WW - 1);
                int i00 = cy0 * WW + cx0, i01 = cy0 * WW + cx1;
                int i10 = cy1 * WW + cx0, i11 = cy1 * WW + cx1;
                const float* x0p = xg;
                const float* x1p = xg + HWW;
                const float* x2p = xg + 2 * HWW;
                const float* x3p = xg + 3 * HWW;
                v0 = w00 * x0p[i00] + w01 * x0p[i01] + w10 * x0p[i10] + w11 * x0p[i11];
                v1 = w00 * x1p[i00] + w01 * x1p[i01] + w10 * x1p[i10] + w11 * x1p[i11];
                v2 = w00 * x2p[i00] + w01 * x2p[i01] + w10 * x2p[i10] + w11 * x2p[i11];
                v3 = w00 * x3p[i00] + w01 * x3p[i01] + w10 * x3p[i10] + w11 * x3p[i11];
            }
            // truncation hi/lo split (4 VALU/value)
            unsigned u0 = __float_as_uint(v0), u1 = __float_as_uint(v1);
            unsigned u2 = __float_as_uint(v2), u3 = __float_as_uint(v3);
            unsigned h0 = u0 & 0xFFFF0000u, h1 = u1 & 0xFFFF0000u;
            unsigned h2 = u2 & 0xFFFF0000u, h3 = u3 & 0xFFFF0000u;
            float r0 = v0 - __uint_as_float(h0), r1 = v1 - __uint_as_float(h1);
            float r2 = v2 - __uint_as_float(h2), r3 = v3 - __uint_as_float(h3);
            uint2 hw, lw;
            hw.x = (u0 >> 16) | h1;
            hw.y = (u2 >> 16) | h3;
            lw.x = pack_hi2(r0, r1);
            lw.y = pack_hi2(r2, r3);
            *(uint2*)&vhf[buf][pix][cg * 2] = hw;
            *(uint2*)&vlf[buf][pix][cg * 2] = lw;
            __syncthreads();
#pragma unroll
            for (int s2 = 0; s2 < 2; s2++) {
                const bf8 bh = *(const bf8*)&vhf[buf][s2 * 16 + (lane & 15)][(lane >> 4) * 4];
                const bf8 bl = *(const bf8*)&vlf[buf][s2 * 16 + (lane & 15)][(lane >> 4) * 4];
                acc[s2] = __builtin_amdgcn_mfma_f32_16x16x32_bf16(ah, bh, acc[s2], 0, 0, 0);
                acc[s2] = __builtin_amdgcn_mfma_f32_16x16x32_bf16(ah, bl, acc[s2], 0, 0, 0);
                acc[s2] = __builtin_amdgcn_mfma_f32_16x16x32_bf16(al, bh, acc[s2], 0, 0, 0);
            }
        }
    };

    // =========================== block timeline ===========================
    stage(1);
    __syncthreads();
    om_pass(1);
    __syncthreads();          // Xs2(half1) reads done before restage
    stage(0);
    __syncthreads();
    om_pass(0);               // Xs2 now holds half 0 (kept for main_pass(0))

    // om epilogue -> omL (union with vhf region; unused until main loop)
    float* omL = (float*)&vhf[0][0][0];   // 27*32 floats = 3,456 B < 10,752 B
    {
        int og = wv & 1, s = wv >> 1;
#pragma unroll
        for (int rg = 0; rg < 4; rg++) {
            int m = og * 16 + (lane >> 4) * 4 + rg;
            if (m < 27) {
                int pp = s * 16 + (lane & 15);
                float v = accom[rg] + om_bias[m];
                if (m >= 18) v = 1.f / (1.f + expf(-v));
                omL[m * 32 + pp] = v;
            }
        }
    }
    __syncthreads();

    // phase B: sampling params per (tap, pixel)
#pragma unroll 1
    for (int it = t; it < 288; it += 256) {
        int k  = it >> 5;
        int pp = it & 31;
        float oy = omL[k * 32 + pp];
        float ox = omL[(9 + k) * 32 + pp];
        float mm = omL[(18 + k) * 32 + pp];
        int ky = k / 3, kx = k - ky * 3;
        float py = oy + (float)(ho + ky - 1);
        float px = ox + (float)(w0 + pp + kx - 1);
        float fy = floorf(py), fx = floorf(px);
        float ly = py - fy, lx = px - fx;
        int y0 = (int)fy, x0 = (int)fx;
        bool vy0 = (y0 >= 0) & (y0 < HH);
        bool vy1 = (y0 + 1 >= 0) & (y0 + 1 < HH);
        bool vx0 = (x0 >= 0) & (x0 < WW);
        bool vx1 = (x0 + 1 >= 0) & (x0 + 1 < WW);
        swt[0][it] = (vy0 & vx0) ? (1.f - ly) * (1.f - lx) * mm : 0.f;
        swt[1][it] = (vy0 & vx1) ? (1.f - ly) * lx * mm : 0.f;
        swt[2][it] = (vy1 & vx0) ? ly * (1.f - lx) * mm : 0.f;
        swt[3][it] = (vy1 & vx1) ? ly * lx * mm : 0.f;
        bool inw = (y0 >= ho - 2) & (y0 <= ho + 1) & (x0 >= w0 - 2) & (x0 <= w0 + 32);
        int y0c = min(max(y0, -8), 135);
        int x0c = min(max(x0, -8), 135);
        sidx[it] = ((y0c + 16) << 16) | ((x0c + 16) & 0xFFFF)
                 | (inw ? 0 : (int)0x80000000);
    }
    __syncthreads();

    main_pass(0);             // Xs2 holds half 0
    stage(1);                 // safe: all Xs2 reads done before tap-8 barrier
    __syncthreads();
    main_pass(1);

    // epilogue
    int prow = ho * WW + w0;
#pragma unroll
    for (int s = 0; s < 2; s++) {
#pragma unroll
        for (int rg = 0; rg < 4; rg++) {
            int o  = wv * 16 + (lane >> 4) * 4 + rg;
            int pp = s * 16 + (lane & 15);
            out[((size_t)(b * OO + o)) * HWW + prow + pp] = acc[s][rg] + bias[o];
        }
    }
}

// ---------------------------------------------------------------------------
extern "C" void kernel_launch(void* const* d_in, const int* in_sizes, int n_in,
                              void* d_out, int out_size, void* d_ws, size_t ws_size,
                              hipStream_t stream)
{
    (void)in_sizes; (void)n_in; (void)out_size; (void)ws_size;
    const float* x      = (const float*)d_in[0];
    const float* weight = (const float*)d_in[1];
    const float* bias   = (const float*)d_in[2];
    const float* om_w   = (const float*)d_in[3];
    const float* om_b   = (const float*)d_in[4];
    float* out = (float*)d_out;
    char*  ws  = (char*)d_ws;

    unsigned short* whf  = (unsigned short*)(ws + WHF_OFF);
    unsigned short* wlf  = (unsigned short*)(ws + WLF_OFF);
    unsigned short* womh = (unsigned short*)(ws + WOMH_OFF);
    unsigned short* woml = (unsigned short*)(ws + WOML_OFF);

    int prep_n = 18 * 4 * 64 * 8 + 18 * 2 * 64 * 8;  // 55296
    prep_kernel<<<(prep_n + 255) / 256, 256, 0, stream>>>(weight, om_w, whf, wlf, womh, woml);

    int nblk = BB * HH * (WW / 32);  // 2048
    fused_kernel<<<nblk, 256, 0, stream>>>(x, whf, wlf, womh, woml, bias, om_b, out);
}